// Round 1
// 296.257 us; speedup vs baseline: 1.0197x; 1.0197x over previous
//
#include <hip/hip_runtime.h>
#include <hip/hip_bf16.h>

typedef unsigned int u32;
typedef unsigned short u16;
typedef __bf16 bf16x8 __attribute__((ext_vector_type(8)));
typedef float f32x4 __attribute__((ext_vector_type(4)));

// ---------- bf16 bit helpers ----------
__device__ __forceinline__ float b2f(u16 s){ union{u32 x; float f;} c; c.x = ((u32)s) << 16; return c.f; }
__device__ __forceinline__ float b2f_lo(u32 u){ union{u32 x; float f;} c; c.x = u << 16; return c.f; }
__device__ __forceinline__ float b2f_hi(u32 u){ union{u32 x; float f;} c; c.x = u & 0xFFFF0000u; return c.f; }
__device__ __forceinline__ u16 f2b(float f){
    union{float f; u32 u;} c; c.f = f;
    u32 r = c.u + 0x7FFFu + ((c.u >> 16) & 1u);
    return (u16)(r >> 16);
}
__device__ __forceinline__ u32 pk(float lo, float hi){
    return (u32)f2b(lo) | ((u32)f2b(hi) << 16);
}
// async global->LDS, 16B per lane (HW: wave-uniform base + lane*16)
__device__ __forceinline__ void gl_lds16(const u16* g, u16* l){
    __builtin_amdgcn_global_load_lds(
        (const __attribute__((address_space(1))) void*)g,
        (__attribute__((address_space(3))) void*)l, 16, 0, 0);
}
#define BARRIER() do { __builtin_amdgcn_s_barrier(); asm volatile("" ::: "memory"); } while(0)

// Problem constants: B=4, T=2048, D=1024, H=16, HD=64, NF=128, chunk C=128, NC=16
// All inputs FLOAT32; OUTPUT is FLOAT32.

// ---------- fp32 -> bf16 bulk convert (x) ----------
__global__ __launch_bounds__(256) void tobf16(const float* __restrict__ in, u16* __restrict__ out)
{
    size_t i = ((size_t)blockIdx.x * 256 + threadIdx.x) * 8;
    float4 a = *reinterpret_cast<const float4*>(in + i);
    float4 b = *reinterpret_cast<const float4*>(in + i + 4);
    uint4 v; v.x = pk(a.x, a.y); v.y = pk(a.z, a.w); v.z = pk(b.x, b.y); v.w = pk(b.z, b.w);
    *reinterpret_cast<uint4*>(out + i) = v;
}

// ---------- all 4 weight transposes (+fp32->bf16) in one dispatch ----------
__global__ __launch_bounds__(256) void transpose_all(const float* __restrict__ Wq, const float* __restrict__ Wk,
                                                     const float* __restrict__ Wv, const float* __restrict__ Wo,
                                                     u16* __restrict__ WTqkv, u16* __restrict__ WTo)
{
    const float* in; u16* out;
    switch (blockIdx.z){
        case 0:  in = Wq; out = WTqkv;           break;
        case 1:  in = Wk; out = WTqkv + 1048576; break;
        case 2:  in = Wv; out = WTqkv + 2097152; break;
        default: in = Wo; out = WTo;             break;
    }
    __shared__ u16 tile[64][72];
    int kb = blockIdx.x * 64, nb = blockIdx.y * 64, tid = threadIdx.x;
#pragma unroll
    for (int i = 0; i < 2; i++){
        int idx = tid + 256*i; int r = idx >> 3; int c8 = (idx & 7) * 8;
        const float* p = &in[(size_t)(kb + r)*1024 + nb + c8];
        float4 lo = *reinterpret_cast<const float4*>(p);
        float4 hi = *reinterpret_cast<const float4*>(p + 4);
        uint4 v;
        v.x = pk(lo.x, lo.y); v.y = pk(lo.z, lo.w);
        v.z = pk(hi.x, hi.y); v.w = pk(hi.z, hi.w);
        *reinterpret_cast<uint4*>(&tile[r][c8]) = v;
    }
    __syncthreads();
#pragma unroll
    for (int i = 0; i < 2; i++){
        int idx = tid + 256*i; int c = idx >> 3; int r8 = (idx & 7) * 8;
        u32 w[4];
#pragma unroll
        for (int j = 0; j < 4; j++)
            w[j] = (u32)tile[r8 + 2*j][c] | ((u32)tile[r8 + 2*j + 1][c] << 16);
        uint4 v; v.x = w[0]; v.y = w[1]; v.z = w[2]; v.w = w[3];
        *reinterpret_cast<uint4*>(&out[(size_t)(nb + c)*1024 + kb + r8]) = v;
    }
}

// ---------- 8-phase counted-vmcnt MFMA bf16 GEMM (T2+T3+T4+T5), tile 256x128, BK=64 ----------
// C[8192,N] = A[8192,1024] * W, BT = bf16 W^T (N x 1024 row-major)
// MODE 2: write fp32 row-major (final output), N=1024, grid (32,8)
// MODE 3: fused QKV: N=3072, write bf16 remapped (which,B,H,T,HD), grid (32,24)
// 512 threads = 8 waves (4M x 2N), per-wave C = 64x64 (acc[4][4]).
// LDS: 2 bufs x { A 256x64 swz (32KB) + B 128x64 swz (16KB) } = 96KB -> 1 block/CU.
// Swizzle: u16 phys = row*64 + (col ^ ((row&7)<<3)); staged via inverse-swizzled GLOBAL src
// (global_load_lds dest is linear, rule #21), read back with the same XOR.
// Pipeline: tile t+2's halves {A0,A1,B} issued at phases 1/1/2 of tile t's compute,
// progressively overwriting buf[t&1]; read deadlines (all A + B.k0 @P0, B.k1 @P1) are
// strictly before each region's overwrite, fenced by barrier+lgkmcnt(0)+barrier per phase.
// One s_waitcnt vmcnt(6) per K-tile (phase 3) retires tile t+1's 6 loads; never 0 mid-loop.
template<int MODE>
__global__ __launch_bounds__(512, 2) void gemm_8p(const u16* __restrict__ A, const u16* __restrict__ BT,
                                                  float* __restrict__ outf, u16* __restrict__ outh)
{
    constexpr int NT = 16;            // K/BK = 1024/64
    __shared__ u16 lds[2][24576];     // per buf: [0,16384)=A, [16384,24576)=B
    const int tid = threadIdx.x;
    const int w = tid >> 6, l = tid & 63;
    const int wr = w >> 1, wc = w & 1;
    const int fr = l & 15, q = l >> 4;
    const int m0 = blockIdx.x * 256, n0 = blockIdx.y * 128;

    // staging: thread (w,l), issue i stages row (w*16 + (l>>3) + i*8) of a 128-row half,
    // 16B at inverse-swizzled col so the linear LDS landing matches the swizzled read.
    const int srow = w*16 + (l >> 3);
    const int scol = ((l & 7) ^ (srow & 7)) << 3;
    const u16* Ag = A  + (size_t)(m0 + srow) * 1024 + scol;
    const u16* Bg = BT + (size_t)(n0 + srow) * 1024 + scol;
    const int sd = w*1024 + l*8;      // u16 LDS dest within a half (+i*512, + region base)

    // fragment read offsets (u16 units): phys = row*64 + ((kk*32+q*8) ^ ((row&7)<<3)); row&7==fr&7
    const int colk0 = (q*8)      ^ ((fr & 7) << 3);
    const int colk1 = (32 + q*8) ^ ((fr & 7) << 3);
    const int arow = (wr*64 + fr) * 64;
    const int brow = 16384 + (wc*64 + fr) * 64;

    f32x4 acc[4][4] = {};

    // prologue: stage tiles 0,1 fully (12 issues/thread), retire tile 0 (vmcnt(6))
#pragma unroll
    for (int kt = 0; kt < 2; ++kt){
        u16* Lb = lds[kt];
#pragma unroll
        for (int i = 0; i < 2; ++i){
            gl_lds16(Ag + (size_t)(i*8)*1024       + kt*64, Lb + sd + i*512);
            gl_lds16(Ag + (size_t)(128 + i*8)*1024 + kt*64, Lb + 8192 + sd + i*512);
            gl_lds16(Bg + (size_t)(i*8)*1024       + kt*64, Lb + 16384 + sd + i*512);
        }
    }
    asm volatile("s_waitcnt vmcnt(6)" ::: "memory");
    __builtin_amdgcn_sched_barrier(0);
    BARRIER();

    for (int t = 0; t < NT; ++t){
        u16* Lb = lds[t & 1];
        const int kt = t + 2;
        const bool st = (kt < NT);
        bf16x8 af[4][2], bfr[4][2];

        // ---- phase 0: ds_read all A (8) + B.k0 (4); MFMA m0-1 x k0 ----
#pragma unroll
        for (int i = 0; i < 4; ++i){
            af[i][0] = *reinterpret_cast<const bf16x8*>(Lb + arow + i*1024 + colk0);
            af[i][1] = *reinterpret_cast<const bf16x8*>(Lb + arow + i*1024 + colk1);
        }
#pragma unroll
        for (int j = 0; j < 4; ++j)
            bfr[j][0] = *reinterpret_cast<const bf16x8*>(Lb + brow + j*1024 + colk0);
        __builtin_amdgcn_s_barrier();
        asm volatile("s_waitcnt lgkmcnt(0)" ::: "memory");
        __builtin_amdgcn_sched_barrier(0);
        __builtin_amdgcn_s_setprio(1);
#pragma unroll
        for (int i = 0; i < 2; ++i)
#pragma unroll
            for (int j = 0; j < 4; ++j)
                acc[i][j] = __builtin_amdgcn_mfma_f32_16x16x32_bf16(af[i][0], bfr[j][0], acc[i][j], 0, 0, 0);
        __builtin_amdgcn_s_setprio(0);
        __builtin_amdgcn_sched_barrier(0);
        BARRIER();

        // ---- phase 1: ds_read B.k1 (4); stage A0+A1 of t+2 (4 issues); MFMA m2-3 x k0 ----
#pragma unroll
        for (int j = 0; j < 4; ++j)
            bfr[j][1] = *reinterpret_cast<const bf16x8*>(Lb + brow + j*1024 + colk1);
        if (st){
#pragma unroll
            for (int i = 0; i < 2; ++i){
                gl_lds16(Ag + (size_t)(i*8)*1024       + kt*64, Lb + sd + i*512);
                gl_lds16(Ag + (size_t)(128 + i*8)*1024 + kt*64, Lb + 8192 + sd + i*512);
            }
        }
        __builtin_amdgcn_s_barrier();
        asm volatile("s_waitcnt lgkmcnt(0)" ::: "memory");
        __builtin_amdgcn_sched_barrier(0);
        __builtin_amdgcn_s_setprio(1);
#pragma unroll
        for (int i = 2; i < 4; ++i)
#pragma unroll
            for (int j = 0; j < 4; ++j)
                acc[i][j] = __builtin_amdgcn_mfma_f32_16x16x32_bf16(af[i][0], bfr[j][0], acc[i][j], 0, 0, 0);
        __builtin_amdgcn_s_setprio(0);
        __builtin_amdgcn_sched_barrier(0);
        BARRIER();

        // ---- phase 2: stage B of t+2 (2 issues); MFMA m0-1 x k1 ----
        if (st){
#pragma unroll
            for (int i = 0; i < 2; ++i)
                gl_lds16(Bg + (size_t)(i*8)*1024 + kt*64, Lb + 16384 + sd + i*512);
        }
        __builtin_amdgcn_s_barrier();
        __builtin_amdgcn_s_setprio(1);
#pragma unroll
        for (int i = 0; i < 2; ++i)
#pragma unroll
            for (int j = 0; j < 4; ++j)
                acc[i][j] = __builtin_amdgcn_mfma_f32_16x16x32_bf16(af[i][1], bfr[j][1], acc[i][j], 0, 0, 0);
        __builtin_amdgcn_s_setprio(0);
        __builtin_amdgcn_sched_barrier(0);
        BARRIER();

        // ---- phase 3: MFMA m2-3 x k1; counted vmcnt retires tile t+1; barrier publishes it ----
        __builtin_amdgcn_s_setprio(1);
#pragma unroll
        for (int i = 2; i < 4; ++i)
#pragma unroll
            for (int j = 0; j < 4; ++j)
                acc[i][j] = __builtin_amdgcn_mfma_f32_16x16x32_bf16(af[i][1], bfr[j][1], acc[i][j], 0, 0, 0);
        __builtin_amdgcn_s_setprio(0);
        __builtin_amdgcn_sched_barrier(0);
        if (t < NT - 2)
            asm volatile("s_waitcnt vmcnt(6)" ::: "memory");
        else
            asm volatile("s_waitcnt vmcnt(0)" ::: "memory");
        __builtin_amdgcn_sched_barrier(0);
        BARRIER();
    }

    // epilogue: C/D layout col=lane&15 (N), row=(lane>>4)*4+r (M)
#pragma unroll
    for (int i = 0; i < 4; i++){
        int row0 = m0 + wr*64 + i*16 + q*4;
#pragma unroll
        for (int j = 0; j < 4; j++){
            int col = n0 + wc*64 + j*16 + fr;
#pragma unroll
            for (int r = 0; r < 4; r++){
                float val = acc[i][j][r];
                int row = row0 + r;
                if (MODE == 2){
                    outf[(size_t)row*1024 + col] = val;
                } else {
                    int which = col >> 10, colw = col & 1023;
                    int h = colw >> 6, d = colw & 63;
                    int bb = row >> 11, tt = row & 2047;
                    outh[(size_t)which*8388608 + (((size_t)(bb*16 + h))*2048 + tt)*64 + d] = f2b(val);
                }
            }
        }
    }
}

// ---------- FAVOR+ feature map via MFMA (q path): phi = exp(x.Wf - 0.5||x||^2)/sqrt(NF) ----------
__global__ __launch_bounds__(256) void featmap_mfma(const u16* __restrict__ xh, const float* __restrict__ Wf,
                                                    u16* __restrict__ xp)
{
    __shared__ u16 Xl[128][72];
    __shared__ u16 Wft[128][72];
    __shared__ float sqp[128][8];
    __shared__ float sql[128];
    int tid = threadIdx.x;
    int lane = tid & 63, w = tid >> 6;
    int m = lane & 15, q = lane >> 4;
    const u16* xb = xh + (size_t)blockIdx.x * 128 * 64;
#pragma unroll
    for (int it = 0; it < 4; it++){
        int idx = tid + 256*it;
        int row = idx >> 3, c8 = (idx & 7) * 8;
        uint4 v = *reinterpret_cast<const uint4*>(xb + (size_t)row*64 + c8);
        *reinterpret_cast<uint4*>(&Xl[row][c8]) = v;
        u32 ww[4] = {v.x, v.y, v.z, v.w};
        float s = 0.f;
#pragma unroll
        for (int j = 0; j < 4; j++){
            float a = b2f_lo(ww[j]), bb = b2f_hi(ww[j]);
            s += a*a + bb*bb;
        }
        sqp[row][idx & 7] = s;
    }
#pragma unroll
    for (int it = 0; it < 8; it++){
        int idx = tid + 256*it;
        int d = idx >> 5, f4 = (idx & 31) * 4;
        float4 v = *reinterpret_cast<const float4*>(Wf + d*128 + f4);
        Wft[f4+0][d] = f2b(v.x); Wft[f4+1][d] = f2b(v.y);
        Wft[f4+2][d] = f2b(v.z); Wft[f4+3][d] = f2b(v.w);
    }
    __syncthreads();
    if (tid < 128){
        float s = 0.f;
#pragma unroll
        for (int j = 0; j < 8; j++) s += sqp[tid][j];
        sql[tid] = s;
    }
    f32x4 acc[2][8] = {};
#pragma unroll
    for (int ks = 0; ks < 2; ks++){
        bf16x8 af[2], bf[8];
#pragma unroll
        for (int mt = 0; mt < 2; mt++)
            af[mt] = *reinterpret_cast<const bf16x8*>(&Xl[32*w + mt*16 + m][ks*32 + q*8]);
#pragma unroll
        for (int nt = 0; nt < 8; nt++)
            bf[nt] = *reinterpret_cast<const bf16x8*>(&Wft[nt*16 + m][ks*32 + q*8]);
#pragma unroll
        for (int mt = 0; mt < 2; mt++)
#pragma unroll
            for (int nt = 0; nt < 8; nt++)
                acc[mt][nt] = __builtin_amdgcn_mfma_f32_16x16x32_bf16(af[mt], bf[nt], acc[mt][nt], 0, 0, 0);
    }
    __syncthreads();
    const float c = 0.08838834764831845f; // 1/sqrt(128)
    u16* xpb = xp + (size_t)blockIdx.x * 128 * 128;
#pragma unroll
    for (int mt = 0; mt < 2; mt++){
#pragma unroll
        for (int r = 0; r < 4; r++){
            int t = 32*w + mt*16 + q*4 + r;
            float hs = 0.5f * sql[t];
#pragma unroll
            for (int nt = 0; nt < 8; nt++){
                int f = nt*16 + m;
                xpb[(size_t)t*128 + f] = f2b(__expf(fminf(acc[mt][nt][r] - hs, 60.f)) * c);
            }
        }
    }
}

// ---------- k path: featmap + per-chunk KV summary fused ----------
// One block = one (bh, chunk): computes kp = phi(k), S^T[d][f] = V^T.kp (MFMA), z = colsum(kp).
struct FM1 { u16 Xl[128][72]; u16 Wft[128][72]; };
union  FMU { FM1 p1; u16 Kpt[128][136]; };
__global__ __launch_bounds__(256) void featmap_sum(const u16* __restrict__ kh, const float* __restrict__ Wf,
                                                   const u16* __restrict__ vh, u16* __restrict__ kp,
                                                   u16* __restrict__ Sa, float* __restrict__ zs)
{
    __shared__ FMU sm;
    __shared__ u16 Vt[64][136];
    __shared__ float sqp[128][8];
    __shared__ float sql[128];
    int blk = blockIdx.x, tid = threadIdx.x;
    int lane = tid & 63, w = tid >> 6;
    int m = lane & 15, q = lane >> 4;
    const u16* xb = kh + (size_t)blk * 128 * 64;
    const u16* vb = vh + (size_t)blk * 128 * 64;   // same (bh,chunk) flat layout
    // stage K-chunk + sq partials
#pragma unroll
    for (int it = 0; it < 4; it++){
        int idx = tid + 256*it;
        int row = idx >> 3, c8 = (idx & 7) * 8;
        uint4 v = *reinterpret_cast<const uint4*>(xb + (size_t)row*64 + c8);
        *reinterpret_cast<uint4*>(&sm.p1.Xl[row][c8]) = v;
        u32 ww[4] = {v.x, v.y, v.z, v.w};
        float s = 0.f;
#pragma unroll
        for (int j = 0; j < 4; j++){
            float a = b2f_lo(ww[j]), bb = b2f_hi(ww[j]);
            s += a*a + bb*bb;
        }
        sqp[row][idx & 7] = s;
    }
    // stage Wf^T
#pragma unroll
    for (int it = 0; it < 8; it++){
        int idx = tid + 256*it;
        int d = idx >> 5, f4 = (idx & 31) * 4;
        float4 v = *reinterpret_cast<const float4*>(Wf + d*128 + f4);
        sm.p1.Wft[f4+0][d] = f2b(v.x); sm.p1.Wft[f4+1][d] = f2b(v.y);
        sm.p1.Wft[f4+2][d] = f2b(v.z); sm.p1.Wft[f4+3][d] = f2b(v.w);
    }
    // stage V transposed
#pragma unroll
    for (int it = 0; it < 4; it++){
        int idx = tid + 256*it;
        int t = idx >> 3, d8 = (idx & 7)*8;
        uint4 v = *reinterpret_cast<const uint4*>(vb + (size_t)t*64 + d8);
        u32 ww[4] = {v.x, v.y, v.z, v.w};
#pragma unroll
        for (int j = 0; j < 4; j++){
            Vt[d8 + 2*j][t]     = (u16)(ww[j] & 0xFFFFu);
            Vt[d8 + 2*j + 1][t] = (u16)(ww[j] >> 16);
        }
    }
    __syncthreads();
    if (tid < 128){
        float s = 0.f;
#pragma unroll
        for (int j = 0; j < 8; j++) s += sqp[tid][j];
        sql[tid] = s;
    }
    // phi MFMA
    f32x4 acc[2][8] = {};
#pragma unroll
    for (int ks = 0; ks < 2; ks++){
        bf16x8 af[2], bf[8];
#pragma unroll
        for (int mt = 0; mt < 2; mt++)
            af[mt] = *reinterpret_cast<const bf16x8*>(&sm.p1.Xl[32*w + mt*16 + m][ks*32 + q*8]);
#pragma unroll
        for (int nt = 0; nt < 8; nt++)
            bf[nt] = *reinterpret_cast<const bf16x8*>(&sm.p1.Wft[nt*16 + m][ks*32 + q*8]);
#pragma unroll
        for (int mt = 0; mt < 2; mt++)
#pragma unroll
            for (int nt = 0; nt < 8; nt++)
                acc[mt][nt] = __builtin_amdgcn_mfma_f32_16x16x32_bf16(af[mt], bf[nt], acc[mt][nt], 0, 0, 0);
    }
    __syncthreads();   // Xl/Wft reads complete (region about to be overwritten), sql visible
    // epilogue: phi -> global kp AND transposed LDS Kpt[f][t]
    const float c = 0.08838834764831845f;
    u16* xpb = kp + (size_t)blk * 128 * 128;
#pragma unroll
    for (int mt = 0; mt < 2; mt++){
#pragma unroll
        for (int r = 0; r < 4; r++){
            int t = 32*w + mt*16 + q*4 + r;
            float hs = 0.5f * sql[t];
#pragma unroll
            for (int nt = 0; nt < 8; nt++){
                int f = nt*16 + m;
                u16 pv = f2b(__expf(fminf(acc[mt][nt][r] - hs, 60.f)) * c);
                xpb[(size_t)t*128 + f] = pv;
                sm.Kpt[f][t] = pv;
            }
        }
    }
    __syncthreads();   // Kpt ready
    // S^T = V^T . kp : A[d][t]=Vt, B[f][t]=Kpt ; wave w -> d rows [16w,16w+16)
    f32x4 acc2[8] = {};
#pragma unroll
    for (int ks = 0; ks < 4; ks++){
        bf16x8 af = *reinterpret_cast<const bf16x8*>(&Vt[16*w + m][ks*32 + q*8]);
        bf16x8 bf[8];
#pragma unroll
        for (int nt = 0; nt < 8; nt++)
            bf[nt] = *reinterpret_cast<const bf16x8*>(&sm.Kpt[nt*16 + m][ks*32 + q*8]);
#pragma unroll
        for (int nt = 0; nt < 8; nt++)
            acc2[nt] = __builtin_amdgcn_mfma_f32_16x16x32_bf16(af, bf[nt], acc2[nt], 0, 0, 0);
    }
    u16* Sb = Sa + (size_t)blk*8192;
#pragma unroll
    for (int nt = 0; nt < 8; nt++){
#pragma unroll
        for (int r = 0; r < 4; r++){
            int d = 16*w + q*4 + r;
            int f = nt*16 + m;
            Sb[(size_t)d*128 + f] = f2b(acc2[nt][r]);
        }
    }
    // z = colsum(kp) from Kpt rows (17-stride bank walk: 2-way, free)
    if (tid < 128){
        float z = 0.f;
#pragma unroll
        for (int t = 0; t < 128; t++) z += b2f(sm.Kpt[tid][t]);
        zs[(size_t)blk*128 + tid] = z;
    }
}

// ---------- exclusive prefix over the 16 chunks (per bh), bf16 in/out ----------
__global__ __launch_bounds__(256) void prefix_chunks(const u16* __restrict__ Sa, u16* __restrict__ Sb,
                                                     float* __restrict__ zs)
{
    int bh = blockIdx.x, seg = blockIdx.y, tid = threadIdx.x;
    const u16* src = Sa + (size_t)bh*16*8192;
    u16*       dst = Sb + (size_t)bh*16*8192;
#pragma unroll
    for (int it = 0; it < 4; it++){
        int e = seg*1024 + it*256 + tid;
        float run = 0.f;
#pragma unroll
        for (int c = 0; c < 16; c++){
            float v = b2f(src[(size_t)c*8192 + e]);
            dst[(size_t)c*8192 + e] = f2b(run);
            run += v;
        }
    }
    if (seg == 0 && tid < 128){
        float run = 0.f; float* zp = zs + (size_t)bh*16*128 + tid;
#pragma unroll
        for (int c = 0; c < 16; c++){ float v = zp[c*128]; zp[c*128] = run; run += v; }
    }
}

// ---------- per-chunk output via MFMA; denominator fused as extra MFMA B-tiles ----------
__global__ __launch_bounds__(256) void chunk_out(const u16* __restrict__ qp, const u16* __restrict__ kp,
                                                 const u16* __restrict__ vh, const u16* __restrict__ St,
                                                 const float* __restrict__ zs, u16* __restrict__ y2d)
{
    __shared__ u16 P[128][136];
    __shared__ u16 Vt[64][136];
    __shared__ u16 zl[128];
    int blk = blockIdx.x, tid = threadIdx.x;
    int lane = tid & 63, w = tid >> 6;
    int m = lane & 15, q = lane >> 4;
    int bh = blk >> 4, c = blk & 15;
    int b = bh >> 4, h = bh & 15, t0 = c*128;
    const u16* qpb = qp + ((size_t)bh*2048 + t0)*128;
    const u16* kpb = kp + ((size_t)bh*2048 + t0)*128;
    const u16* vb  = vh + ((size_t)bh*2048 + t0)*64;
    const u16* Stb = St + (size_t)blk*8192;

    if (tid < 128) zl[tid] = f2b(zs[(size_t)blk*128 + tid]);
#pragma unroll
    for (int it = 0; it < 4; it++){
        int idx = tid + 256*it;
        int t = idx >> 3, d8 = (idx & 7)*8;
        uint4 v = *reinterpret_cast<const uint4*>(&vb[(size_t)t*64 + d8]);
        u32 ww[4] = {v.x, v.y, v.z, v.w};
#pragma unroll
        for (int j = 0; j < 4; j++){
            Vt[d8 + 2*j][t]     = (u16)(ww[j] & 0xFFFFu);
            Vt[d8 + 2*j + 1][t] = (u16)(ww[j] >> 16);
        }
    }
    {
        int row = tid >> 1, half = tid & 1;
        int i = row >> 4;
        for (int s2 = 16*(i + 1) + half*2; s2 < 128; s2 += 4)
            *reinterpret_cast<u32*>(&P[row][s2]) = 0;
    }
    {
        static const unsigned char TIa[36] = {0,1,1,2,2,2,3,3,3,3,4,4,4,4,4,
                                              5,5,5,5,5,5,6,6,6,6,6,6,6,7,7,7,7,7,7,7,7};
        static const unsigned char TJa[36] = {0,0,1,0,1,2,0,1,2,3,0,1,2,3,4,
                                              0,1,2,3,4,5,0,1,2,3,4,5,6,0,1,2,3,4,5,6,7};
        for (int idx = w; idx < 36; idx += 4){
            int i = TIa[idx], j = TJa[idx];
            f32x4 a = {};
            const u16* arow = qpb + (size_t)(i*16 + m)*128 + q*8;
            const u16* brow = kpb + (size_t)(j*16 + m)*128 + q*8;
#pragma unroll
            for (int ks = 0; ks < 4; ks++){
                bf16x8 af = *reinterpret_cast<const bf16x8*>(arow + ks*32);
                bf16x8 bf = *reinterpret_cast<const bf16x8*>(brow + ks*32);
                a = __builtin_amdgcn_mfma_f32_16x16x32_bf16(af, bf, a, 0, 0, 0);
            }
            int scol = j*16 + m;
#pragma unroll
            for (int r = 0; r < 4; r++){
                int trow = i*16 + q*4 + r;
                P[trow][scol] = (scol <= trow) ? f2b(a[r]) : (u16)0;
            }
        }
    }
    __syncthreads();
    f32x4 acc[2][4] = {};
    f32x4 accd[2] = {};
    bf16x8 ones;
#pragma unroll
    for (int i = 0; i < 8; i++) ones[i] = (__bf16)1.0f;
    for (int ks = 0; ks <= w; ks++){
        bf16x8 af[2], bf4[4];
#pragma unroll
        for (int mt = 0; mt < 2; mt++)
            af[mt] = *reinterpret_cast<const bf16x8*>(&P[32*w + mt*16 + m][ks*32 + q*8]);
#pragma unroll
        for (int nt = 0; nt < 4; nt++)
            bf4[nt] = *reinterpret_cast<const bf16x8*>(&Vt[nt*16 + m][ks*32 + q*8]);
#pragma unroll
        for (int mt = 0; mt < 2; mt++){
#pragma unroll
            for (int nt = 0; nt < 4; nt++)
                acc[mt][nt] = __builtin_amdgcn_mfma_f32_16x16x32_bf16(af[mt], bf4[nt], acc[mt][nt], 0, 0, 0);
            accd[mt] = __builtin_amdgcn_mfma_f32_16x16x32_bf16(af[mt], ones, accd[mt], 0, 0, 0);
        }
    }
#pragma unroll
    for (int ks = 0; ks < 4; ks++){
        bf16x8 af[2], bf4[4];
        bf16x8 zf = *reinterpret_cast<const bf16x8*>(&zl[ks*32 + q*8]);
#pragma unroll
        for (int mt = 0; mt < 2; mt++)
            af[mt] = *reinterpret_cast<const bf16x8*>(qpb + (size_t)(32*w + mt*16 + m)*128 + ks*32 + q*8);
#pragma unroll
        for (int nt = 0; nt < 4; nt++)
            bf4[nt] = *reinterpret_cast<const bf16x8*>(Stb + (size_t)(nt*16 + m)*128 + ks*32 + q*8);
#pragma unroll
        for (int mt = 0; mt < 2; mt++){
#pragma unroll
            for (int nt = 0; nt < 4; nt++)
                acc[mt][nt] = __builtin_amdgcn_mfma_f32_16x16x32_bf16(af[mt], bf4[nt], acc[mt][nt], 0, 0, 0);
            accd[mt] = __builtin_amdgcn_mfma_f32_16x16x32_bf16(af[mt], zf, accd[mt], 0, 0, 0);
        }
    }
#pragma unroll
    for (int mt = 0; mt < 2; mt++){
#pragma unroll
        for (int nt = 0; nt < 4; nt++){
#pragma unroll
            for (int r = 0; r < 4; r++){
                int t = 32*w + mt*16 + q*4 + r;
                int d = nt*16 + m;
                float den = accd[mt][r] + 1e-6f;
                y2d[((size_t)b*2048 + t0 + t)*1024 + h*64 + d] = f2b(acc[mt][nt][r] / den);
            }
        }
    }
}

extern "C" void kernel_launch(void* const* d_in, const int* in_sizes, int n_in,
                              void* d_out, int out_size, void* d_ws, size_t ws_size,
                              hipStream_t stream)
{
    (void)in_sizes; (void)n_in; (void)out_size; (void)ws_size;
    const float* x  = (const float*)d_in[0];
    const float* Wq = (const float*)d_in[1];
    const float* Wk = (const float*)d_in[2];
    const float* Wv = (const float*)d_in[3];
    const float* Wo = (const float*)d_in[4];
    const float* Wf = (const float*)d_in[5];
    float* out = (float*)d_out;
    char* ws = (char*)d_ws;

    // workspace layout (lifetime-aliased, ~136.5 MiB)
    u16*   xh    = (u16*)  (ws + 0);           // 16MB x bf16 (dead after QKV gemm)
    u16*   Sa    = (u16*)  (ws + 0);           // alias xh: chunk S^T raw bf16
    u16*   qh    = (u16*)  (ws + 16777216);    // 16MB (dead after featmap q)
    u16*   Sbp   = (u16*)  (ws + 16777216);    // alias qh: prefix S^T
    u16*   kh    = (u16*)  (ws + 33554432);    // 16MB (dead after featmap_sum)
    u16*   y2d   = (u16*)  (ws + 33554432);    // alias kh
    u16*   vh    = (u16*)  (ws + 50331648);    // 16MB
    u16*   qp    = (u16*)  (ws + 67108864);    // 32MB
    u16*   kp    = (u16*)  (ws + 100663296);   // 32MB
    u16*   WTqkv = (u16*)  (ws + 134217728);   // 6MB (3 x 1024x1024 bf16)
    u16*   WTo   = (u16*)  (ws + 140509184);   // 2MB
    float* zs    = (float*)(ws + 142606336);   // 0.5MB

    tobf16<<<4096, 256, 0, stream>>>(x, xh);
    transpose_all<<<dim3(16, 16, 4), 256, 0, stream>>>(Wq, Wk, Wv, Wo, WTqkv, WTo);

    // fused QKV: writes qh, kh, vh (contiguous 16MB blocks starting at qh)
    gemm_8p<3><<<dim3(32, 24), 512, 0, stream>>>(xh, WTqkv, nullptr, qh);

    featmap_mfma<<<1024, 256, 0, stream>>>(qh, Wf, qp);
    featmap_sum<<<1024, 256, 0, stream>>>(kh, Wf, vh, kp, Sa, zs);

    prefix_chunks<<<dim3(64, 8), 256, 0, stream>>>(Sa, Sbp, zs);
    chunk_out<<<1024, 256, 0, stream>>>(qp, kp, vh, Sbp, zs, y2d);

    gemm_8p<2><<<dim3(32, 8), 512, 0, stream>>>(y2d, WTo, out, nullptr);
}